// Round 1
// baseline (1545.614 us; speedup 1.0000x reference)
//
#include <hip/hip_runtime.h>
#include <hip/hip_bf16.h>

typedef __hip_bfloat16 bf16;

#define DD    172      // D
#define EE    172      // E
#define TT    100      // T
#define HH    2
#define KK    20
#define DHH   86
#define QIN   272      // D+T
#define KVIN  444      // D+E+T
#define F1IN  344      // 2D
#define N0C   512
#define N1C   10240
#define RPB   16       // rows per block in projection/ffn kernels
#define PAD   20       // padded transposed-LDS row stride (floats); 80B keeps float4 alignment

// ---------------- mask dtype probe -------------------------------------
// numpy bool input may arrive as int32 (0/1), uint8 bytes, or float32.
// Classify by scanning the raw words of mask1. mode: 0=int32, 1=byte, 2=float32.
__global__ void probe_mask_kernel(const unsigned* __restrict__ m, int n_ints,
                                  int* __restrict__ mode_out) {
    __shared__ int c_other, c_float;
    if (threadIdx.x == 0) { c_other = 0; c_float = 0; }
    __syncthreads();
    int lo = 0, lf = 0;
    for (int i = threadIdx.x; i < n_ints; i += blockDim.x) {
        unsigned v = m[i];
        if (v == 0x3F800000u) lf++;          // float 1.0 pattern (impossible for byte/int layouts)
        else if (v > 1u) lo++;               // packed bytes produce values like 0x01010101
    }
    if (lo) atomicAdd(&c_other, lo);
    if (lf) atomicAdd(&c_float, lf);
    __syncthreads();
    if (threadIdx.x == 0) {
        int mode = 0;
        if (c_float > 0) mode = 2;
        else if (c_other > 0) mode = 1;
        *mode_out = mode;
    }
}

__device__ __forceinline__ bool get_mask(const void* m, int mode, int idx) {
    if (mode == 1) return ((const unsigned char*)m)[idx] != 0;
    if (mode == 2) return ((const float*)m)[idx] != 0.0f;
    return ((const int*)m)[idx] != 0;
}

// ---------------- weight bf16 conversion (wk, wv, both layers) ----------
__global__ void cvt_bf16_kernel(const float* __restrict__ a, const float* __restrict__ b,
                                bf16* __restrict__ oa, bf16* __restrict__ ob, int n) {
    int i = blockIdx.x * blockDim.x + threadIdx.x;
    if (i < n) {
        oa[i] = __float2bfloat16(a[i]);
        ob[i] = __float2bfloat16(b[i]);
    }
}

// ---------------- Q projection: q = [feat | cos(time_b)] @ wq + bq ------
__global__ __launch_bounds__(192) void proj_q_kernel(
    const float* __restrict__ sf, const int* __restrict__ idx,
    const float* __restrict__ time_b,
    const float* __restrict__ wq, const float* __restrict__ bq,
    float* __restrict__ qout) {
    __shared__ __align__(16) float qin_t[QIN][PAD];
    int base = blockIdx.x * RPB;
    for (int r = 0; r < RPB; r++) {
        int row = base + r;
        const float* src = sf + (size_t)idx[row] * DD;
        for (int i = threadIdx.x; i < QIN; i += blockDim.x) {
            qin_t[i][r] = (i < DD) ? src[i] : cosf(time_b[i - DD]);
        }
    }
    __syncthreads();
    int j = threadIdx.x;
    if (j < DD) {
        float acc[RPB];
#pragma unroll
        for (int r = 0; r < RPB; r++) acc[r] = 0.f;
        for (int i = 0; i < QIN; i++) {
            float w = wq[i * DD + j];
#pragma unroll
            for (int rr = 0; rr < RPB / 4; rr++) {
                float4 a = ((const float4*)&qin_t[i][0])[rr];
                acc[4 * rr + 0] += a.x * w;
                acc[4 * rr + 1] += a.y * w;
                acc[4 * rr + 2] += a.z * w;
                acc[4 * rr + 3] += a.w * w;
            }
        }
        float b = bq[j];
#pragma unroll
        for (int r = 0; r < RPB; r++) qout[(size_t)(base + r) * DD + j] = acc[r] + b;
    }
}

// ---------------- K/V projection (the big GEMM) -------------------------
// kv_in = [nbr_feat(172) | edge(172) | cos(dt*w+b)(100)]; k = kv_in@wk+bk, v likewise.
// layer0: nbr_feat = mask ? z[g2l[g]] : sf[g]. layer1: nbr_feat = sf[g].
__global__ __launch_bounds__(192) void proj_kv_kernel(
    const float* __restrict__ sf, const int* __restrict__ nbrf,
    const float* __restrict__ edge, const float* __restrict__ times,
    const float* __restrict__ nbrt,
    const void* __restrict__ mask, const int* __restrict__ mode_p,
    const float* __restrict__ time_w, const float* __restrict__ time_b,
    const bf16* __restrict__ wk, const float* __restrict__ bk,
    const bf16* __restrict__ wv, const float* __restrict__ bv,
    const float* __restrict__ zbuf, const int* __restrict__ g2l, int use_z,
    bf16* __restrict__ kout, bf16* __restrict__ vout) {
    __shared__ __align__(16) float kvin_t[KVIN][PAD];
    __shared__ float dt_s[RPB];
    __shared__ const float* src_s[RPB];
    int base = blockIdx.x * RPB;
    int mode = *mode_p;
    if (threadIdx.x < RPB) {
        int row = base + threadIdx.x;
        int g = nbrf[row];
        bool mk = get_mask(mask, mode, row);
        dt_s[threadIdx.x] = mk ? (times[row / KK] - nbrt[row]) : 0.f;
        const float* s;
        if (use_z && mk) s = zbuf + (size_t)g2l[g] * DD;
        else             s = sf + (size_t)g * DD;
        src_s[threadIdx.x] = s;
    }
    __syncthreads();
    for (int r = 0; r < RPB; r++) {
        int row = base + r;
        const float* src = src_s[r];
        float dt = dt_s[r];
        for (int i = threadIdx.x; i < KVIN; i += blockDim.x) {
            float v;
            if (i < DD)            v = src[i];
            else if (i < DD + EE)  v = edge[(size_t)row * EE + (i - DD)];
            else { int t = i - DD - EE; v = cosf(dt * time_w[t] + time_b[t]); }
            kvin_t[i][r] = v;
        }
    }
    __syncthreads();
    int j = threadIdx.x;
    if (j < DD) {
        float ak[RPB], av[RPB];
#pragma unroll
        for (int r = 0; r < RPB; r++) { ak[r] = 0.f; av[r] = 0.f; }
        for (int i = 0; i < KVIN; i++) {
            float wkv = __bfloat162float(wk[i * DD + j]);
            float wvv = __bfloat162float(wv[i * DD + j]);
#pragma unroll
            for (int rr = 0; rr < RPB / 4; rr++) {
                float4 a = ((const float4*)&kvin_t[i][0])[rr];
                ak[4 * rr + 0] += a.x * wkv;  av[4 * rr + 0] += a.x * wvv;
                ak[4 * rr + 1] += a.y * wkv;  av[4 * rr + 1] += a.y * wvv;
                ak[4 * rr + 2] += a.z * wkv;  av[4 * rr + 2] += a.z * wvv;
                ak[4 * rr + 3] += a.w * wkv;  av[4 * rr + 3] += a.w * wvv;
            }
        }
        float bk_ = bk[j], bv_ = bv[j];
#pragma unroll
        for (int r = 0; r < RPB; r++) {
            kout[(size_t)(base + r) * DD + j] = __float2bfloat16(ak[r] + bk_);
            vout[(size_t)(base + r) * DD + j] = __float2bfloat16(av[r] + bv_);
        }
    }
}

// ---------------- attention over K=20 neighbors -------------------------
__global__ __launch_bounds__(64) void attn_kernel(
    const float* __restrict__ q, const bf16* __restrict__ kmat,
    const bf16* __restrict__ vmat,
    const void* __restrict__ mask, const int* __restrict__ mode_p,
    float* __restrict__ o) {
    int node = blockIdx.x;
    int tid = threadIdx.x;
    __shared__ float qs[DD];
    __shared__ float sc[HH][KK];
    __shared__ float aw[HH][KK];
    int mode = *mode_p;
    for (int i = tid; i < DD; i += 64) qs[i] = q[(size_t)node * DD + i];
    __syncthreads();
    if (tid < HH * KK) {
        int h = tid / KK, kx = tid % KK;
        bool mk = get_mask(mask, mode, node * KK + kx);
        float s = 0.f;
        const bf16* kr = kmat + ((size_t)node * KK + kx) * DD + h * DHH;
        for (int d = 0; d < DHH; d++) s += qs[h * DHH + d] * __bfloat162float(kr[d]);
        sc[h][kx] = mk ? s * 0.10783277320f : -3.0e38f;   // *1/sqrt(86), masked -> -inf
    }
    __syncthreads();
    if (tid < HH) {
        int h = tid;
        float m = -3.0e38f;
        for (int k2 = 0; k2 < KK; k2++) m = fmaxf(m, sc[h][k2]);
        float den = 0.f;
        for (int k2 = 0; k2 < KK; k2++) {
            float e = (sc[h][k2] <= -1e37f) ? 0.f : expf(sc[h][k2] - m);
            sc[h][k2] = e;
            den += e;
        }
        float inv = (den > 0.f) ? 1.f / den : 0.f;
        for (int k2 = 0; k2 < KK; k2++) aw[h][k2] = sc[h][k2] * inv;
    }
    __syncthreads();
    for (int jj = tid; jj < DD; jj += 64) {
        int h = jj / DHH;
        float s = 0.f;
        for (int k2 = 0; k2 < KK; k2++)
            s += aw[h][k2] * __bfloat162float(vmat[((size_t)node * KK + k2) * DD + jj]);
        o[(size_t)node * DD + jj] = s;
    }
}

// ---------------- FFN: h=relu([o|nf]@f1w+f1b); out=h@f2w+f2b -> z[g2l] --
__global__ __launch_bounds__(192) void ffn_kernel(
    const float* __restrict__ o, const float* __restrict__ sf,
    const int* __restrict__ idx,
    const float* __restrict__ f1w, const float* __restrict__ f1b,
    const float* __restrict__ f2w, const float* __restrict__ f2b,
    const int* __restrict__ g2l, float* __restrict__ z) {
    __shared__ __align__(16) float in_t[F1IN][PAD];
    __shared__ __align__(16) float h_t[DD][PAD];
    __shared__ int gid_s[RPB];
    int base = blockIdx.x * RPB;
    if (threadIdx.x < RPB) gid_s[threadIdx.x] = idx[base + threadIdx.x];
    __syncthreads();
    for (int r = 0; r < RPB; r++) {
        int row = base + r;
        const float* src = sf + (size_t)gid_s[r] * DD;
        for (int i = threadIdx.x; i < F1IN; i += blockDim.x)
            in_t[i][r] = (i < DD) ? o[(size_t)row * DD + i] : src[i - DD];
    }
    __syncthreads();
    int j = threadIdx.x;
    if (j < DD) {
        float acc[RPB];
#pragma unroll
        for (int r = 0; r < RPB; r++) acc[r] = 0.f;
        for (int i = 0; i < F1IN; i++) {
            float w = f1w[i * DD + j];
#pragma unroll
            for (int rr = 0; rr < RPB / 4; rr++) {
                float4 a = ((const float4*)&in_t[i][0])[rr];
                acc[4 * rr + 0] += a.x * w;
                acc[4 * rr + 1] += a.y * w;
                acc[4 * rr + 2] += a.z * w;
                acc[4 * rr + 3] += a.w * w;
            }
        }
        float b = f1b[j];
#pragma unroll
        for (int r = 0; r < RPB; r++) h_t[j][r] = fmaxf(acc[r] + b, 0.f);
    }
    __syncthreads();
    if (j < DD) {
        float acc[RPB];
#pragma unroll
        for (int r = 0; r < RPB; r++) acc[r] = 0.f;
        for (int i = 0; i < DD; i++) {
            float w = f2w[i * DD + j];
#pragma unroll
            for (int rr = 0; rr < RPB / 4; rr++) {
                float4 a = ((const float4*)&h_t[i][0])[rr];
                acc[4 * rr + 0] += a.x * w;
                acc[4 * rr + 1] += a.y * w;
                acc[4 * rr + 2] += a.z * w;
                acc[4 * rr + 3] += a.w * w;
            }
        }
        float b = f2b[j];
#pragma unroll
        for (int r = 0; r < RPB; r++) {
            int zr = g2l[gid_s[r]];
            z[(size_t)zr * DD + j] = acc[r] + b;
        }
    }
}

// ---------------- launch ------------------------------------------------
extern "C" void kernel_launch(void* const* d_in, const int* in_sizes, int n_in,
                              void* d_out, int out_size, void* d_ws, size_t ws_size,
                              hipStream_t stream) {
    const float* sf     = (const float*)d_in[0];
    const float* time_w = (const float*)d_in[1];
    const float* time_b = (const float*)d_in[2];
    const float* wq  = (const float*)d_in[3];
    const float* bq  = (const float*)d_in[4];
    const float* wk  = (const float*)d_in[5];
    const float* bk  = (const float*)d_in[6];
    const float* wv  = (const float*)d_in[7];
    const float* bv  = (const float*)d_in[8];
    const float* f1w = (const float*)d_in[9];
    const float* f1b = (const float*)d_in[10];
    const float* f2w = (const float*)d_in[11];
    const float* f2b = (const float*)d_in[12];
    const float* times0 = (const float*)d_in[13];
    const float* nbrt0  = (const float*)d_in[14];
    const float* times1 = (const float*)d_in[15];
    const float* nbrt1  = (const float*)d_in[16];
    const float* edge0  = (const float*)d_in[17];
    const float* edge1  = (const float*)d_in[18];
    const int* nids0 = (const int*)d_in[19];
    const int* nbr0  = (const int*)d_in[20];
    const int* nbr1  = (const int*)d_in[21];
    const int* g2l   = (const int*)d_in[22];
    const void* mask0 = d_in[23];
    const void* mask1 = d_in[24];
    float* z = (float*)d_out;

    char* wsp = (char*)d_ws;
    size_t off = 0;
    auto alloc = [&](size_t bytes) -> void* {
        void* p = wsp + off;
        off += (bytes + 255) & ~(size_t)255;
        return p;
    };
    int* mode   = (int*)alloc(4);
    bf16* wk_bf = (bf16*)alloc((size_t)2 * KVIN * DD * sizeof(bf16));
    bf16* wv_bf = (bf16*)alloc((size_t)2 * KVIN * DD * sizeof(bf16));
    float* q1 = (float*)alloc((size_t)N1C * DD * sizeof(float));
    bf16*  k1 = (bf16*)alloc((size_t)N1C * KK * DD * sizeof(bf16));
    bf16*  v1 = (bf16*)alloc((size_t)N1C * KK * DD * sizeof(bf16));
    float* o1 = (float*)alloc((size_t)N1C * DD * sizeof(float));
    float* q0 = (float*)alloc((size_t)N0C * DD * sizeof(float));
    bf16*  k0 = (bf16*)alloc((size_t)N0C * KK * DD * sizeof(bf16));
    bf16*  v0 = (bf16*)alloc((size_t)N0C * KK * DD * sizeof(bf16));
    float* o0 = (float*)alloc((size_t)N0C * DD * sizeof(float));

    // probe mask dtype (mask1 words; safe length under byte layout)
    probe_mask_kernel<<<1, 256, 0, stream>>>((const unsigned*)mask1, (N1C * KK) / 4, mode);
    // weights to bf16
    int nw = 2 * KVIN * DD;
    cvt_bf16_kernel<<<(nw + 255) / 256, 256, 0, stream>>>(wk, wv, wk_bf, wv_bf, nw);

    // ---- layer 1 (n = N1 = 10240 = rows of nbr0 flat) ----
    proj_q_kernel<<<N1C / RPB, 192, 0, stream>>>(
        sf, nbr0, time_b, wq + (size_t)QIN * DD, bq + DD, q1);
    proj_kv_kernel<<<(N1C * KK) / RPB, 192, 0, stream>>>(
        sf, nbr1, edge1, times1, nbrt1, mask1, mode, time_w, time_b,
        wk_bf + (size_t)KVIN * DD, bk + DD, wv_bf + (size_t)KVIN * DD, bv + DD,
        z, g2l, 0, k1, v1);
    attn_kernel<<<N1C, 64, 0, stream>>>(q1, k1, v1, mask1, mode, o1);
    ffn_kernel<<<N1C / RPB, 192, 0, stream>>>(
        o1, sf, nbr0, f1w + (size_t)F1IN * DD, f1b + DD,
        f2w + (size_t)DD * DD, f2b + DD, g2l, z);

    // ---- layer 0 (n = N0 = 512) ----
    proj_q_kernel<<<N0C / RPB, 192, 0, stream>>>(
        sf, nids0, time_b, wq, bq, q0);
    proj_kv_kernel<<<(N0C * KK) / RPB, 192, 0, stream>>>(
        sf, nbr0, edge0, times0, nbrt0, mask0, mode, time_w, time_b,
        wk_bf, bk, wv_bf, bv, z, g2l, 1, k0, v0);
    attn_kernel<<<N0C, 64, 0, stream>>>(q0, k0, v0, mask0, mode, o0);
    ffn_kernel<<<N0C / RPB, 192, 0, stream>>>(
        o0, sf, nids0, f1w, f1b, f2w, f2b, g2l, z);
}

// Round 2
// 719.137 us; speedup vs baseline: 2.1493x; 2.1493x over previous
//
#include <hip/hip_runtime.h>
#include <hip/hip_bf16.h>

typedef __hip_bfloat16 bf16;
typedef __attribute__((ext_vector_type(8))) short short8;
typedef __attribute__((ext_vector_type(4))) float f32x4;

#define DD    172      // D
#define EE    172      // E
#define TT    100      // T
#define HH    2
#define KK    20
#define DHH   86
#define QIN   272      // D+T
#define KVIN  444      // D+E+T
#define F1IN  344      // 2D
#define N0C   512
#define N1C   10240
#define M1    204800   // N1*K rows
#define M0    10240    // N0*K rows
#define RPB   16
#define PAD   20

// GEMM geometry
#define BM   128
#define BN   176
#define BK   64
#define KP   448       // padded K (444 -> 448)
#define NKV  344       // real N (k|v)
#define NPADR 384      // wkvT rows allocated per layer (>= 176+192)

#define GLOAD(src, dst) __builtin_amdgcn_global_load_lds( \
    (const __attribute__((address_space(1))) unsigned int*)(src), \
    (__attribute__((address_space(3))) unsigned int*)(dst), 16, 0, 0)

// ---------------- mask dtype probe -------------------------------------
__global__ void probe_mask_kernel(const unsigned* __restrict__ m, int n_ints,
                                  int* __restrict__ mode_out) {
    __shared__ int c_other, c_float;
    if (threadIdx.x == 0) { c_other = 0; c_float = 0; }
    __syncthreads();
    int lo = 0, lf = 0;
    for (int i = threadIdx.x; i < n_ints; i += blockDim.x) {
        unsigned v = m[i];
        if (v == 0x3F800000u) lf++;
        else if (v > 1u) lo++;
    }
    if (lo) atomicAdd(&c_other, lo);
    if (lf) atomicAdd(&c_float, lf);
    __syncthreads();
    if (threadIdx.x == 0) {
        int mode = 0;
        if (c_float > 0) mode = 2;
        else if (c_other > 0) mode = 1;
        *mode_out = mode;
    }
}

__device__ __forceinline__ bool get_mask(const void* m, int mode, int idx) {
    if (mode == 1) return ((const unsigned char*)m)[idx] != 0;
    if (mode == 2) return ((const float*)m)[idx] != 0.0f;
    return ((const int*)m)[idx] != 0;
}

// ---------------- weight prep: wkvT[l][n][k] bf16 + fused bias ----------
__global__ void prep_wkvT_kernel(const float* __restrict__ wk, const float* __restrict__ wv,
                                 const float* __restrict__ bk, const float* __restrict__ bv,
                                 bf16* __restrict__ wkvT, float* __restrict__ biaskv) {
    size_t i = (size_t)blockIdx.x * blockDim.x + threadIdx.x;
    size_t tot = (size_t)2 * NPADR * KP;
    if (i >= tot) return;
    int l = (int)(i / ((size_t)NPADR * KP));
    int rem = (int)(i % ((size_t)NPADR * KP));
    int k = rem / NPADR;            // consecutive tid -> consecutive n: coalesced wk reads
    int n = rem % NPADR;
    float v = 0.f;
    if (k < KVIN) {
        if (n < DD)          v = wk[((size_t)l * KVIN + k) * DD + n];
        else if (n < 2 * DD) v = wv[((size_t)l * KVIN + k) * DD + (n - DD)];
    }
    wkvT[((size_t)l * NPADR + n) * KP + k] = __float2bfloat16(v);
    if (i < 2 * 352) {
        int nn = (int)(i % 352), ll = (int)(i / 352);
        biaskv[i] = nn < DD ? bk[ll * DD + nn] : (nn < 2 * DD ? bv[ll * DD + nn - DD] : 0.f);
    }
}

// ---------------- kv_in staging: [nbr_feat | edge | cos(dt*w+b) | 0pad] --
__global__ __launch_bounds__(256) void stage_kvin_kernel(
    const float* __restrict__ sf, const int* __restrict__ nbrs,
    const float* __restrict__ edge, const float* __restrict__ times,
    const float* __restrict__ nbrt,
    const void* __restrict__ mask, const int* __restrict__ mode_p,
    const float* __restrict__ time_w, const float* __restrict__ time_b,
    const float* __restrict__ zbuf, const int* __restrict__ g2l, int use_z,
    int row0, bf16* __restrict__ out) {
    int wave = threadIdx.x >> 6, lane = threadIdx.x & 63;
    int lrow = blockIdx.x * 4 + wave;     // row within chunk
    int row = row0 + lrow;                // global row
    int mode = *mode_p;
    int g = nbrs[row];
    bool mk = get_mask(mask, mode, row);
    float dt = mk ? (times[row / KK] - nbrt[row]) : 0.f;
    const float* src = (use_z && mk) ? (zbuf + (size_t)g2l[g] * DD)
                                     : (sf + (size_t)g * DD);
    const float* erow = edge + (size_t)row * EE;
    bf16* orow = out + (size_t)lrow * KP;
    for (int i = lane; i < KP; i += 64) {
        float v;
        if (i < DD)            v = src[i];
        else if (i < DD + EE)  v = erow[i - DD];
        else if (i < KVIN)     { int t = i - DD - EE; v = cosf(dt * time_w[t] + time_b[t]); }
        else                   v = 0.f;
        orow[i] = __float2bfloat16(v);
    }
}

// ---------------- MFMA GEMM: kv[m][0:344] = A[m][:] @ wkvT^T + bias ------
__global__ __launch_bounds__(256) void gemm_kv_kernel(
    const bf16* __restrict__ A,      // [chunkRows][KP]
    const bf16* __restrict__ BT,     // [NPADR][KP] (layer-offset applied)
    const float* __restrict__ bias,  // [352]
    bf16* __restrict__ kvout,        // [chunkRows][NKV] (chunk base)
    int Mtiles) {
    int mt = blockIdx.x % Mtiles;
    int nt = blockIdx.x / Mtiles;    // 0 or 1
    int m0 = mt * BM;
    int n0 = nt * BN;
    __shared__ bf16 As[BM][BK];      // 16 KB, linear row-major
    __shared__ bf16 Bs[192][BK];     // 24 KB
    int tid = threadIdx.x;
    int lane = tid & 63;
    int wave = tid >> 6;
    int ml = lane & 15;
    int kg = lane >> 4;

    f32x4 acc[2][11];
#pragma unroll
    for (int mg = 0; mg < 2; ++mg)
#pragma unroll
        for (int fn = 0; fn < 11; ++fn)
            acc[mg][fn] = (f32x4){0.f, 0.f, 0.f, 0.f};

    for (int kk = 0; kk < KP; kk += BK) {
        // stage A: 1024 16B chunks; linear LDS dest, pre-swizzled global src
        {
            int c0 = tid;
#pragma unroll
            for (int it = 0; it < 4; ++it) {
                int c = it * 256 + c0;
                int row = c >> 3, slot = c & 7;
                int sslot = slot ^ (row & 7);
                const bf16* src = A + (size_t)(m0 + row) * KP + kk + sslot * 8;
                char* dst = ((char*)As) + (size_t)(it * 256 + wave * 64) * 16;
                GLOAD(src, dst);
            }
            // stage B: 1536 16B chunks (192 rows)
#pragma unroll
            for (int it = 0; it < 6; ++it) {
                int c = it * 256 + c0;
                int row = c >> 3, slot = c & 7;
                int sslot = slot ^ (row & 7);
                const bf16* src = BT + (size_t)(n0 + row) * KP + kk + sslot * 8;
                char* dst = ((char*)Bs) + (size_t)(it * 256 + wave * 64) * 16;
                GLOAD(src, dst);
            }
        }
        __syncthreads();
#pragma unroll
        for (int half = 0; half < 2; ++half) {
            int kc = kg + half * 4;          // k-slot 0..7
            short8 a[2], b[11];
#pragma unroll
            for (int mg = 0; mg < 2; ++mg) {
                int r = wave * 32 + mg * 16 + ml;
                a[mg] = *(const short8*)(((const char*)As) + (size_t)r * 128 + ((size_t)(kc ^ (r & 7)) << 4));
            }
#pragma unroll
            for (int fn = 0; fn < 11; ++fn) {
                int r = fn * 16 + ml;
                b[fn] = *(const short8*)(((const char*)Bs) + (size_t)r * 128 + ((size_t)(kc ^ (r & 7)) << 4));
            }
#pragma unroll
            for (int mg = 0; mg < 2; ++mg)
#pragma unroll
                for (int fn = 0; fn < 11; ++fn)
                    acc[mg][fn] = __builtin_amdgcn_mfma_f32_16x16x32_bf16(a[mg], b[fn], acc[mg][fn], 0, 0, 0);
        }
        __syncthreads();
    }
    // epilogue: C[row][col], col=lane&15 within frag, rows=(lane>>4)*4+reg
#pragma unroll
    for (int mg = 0; mg < 2; ++mg)
#pragma unroll
        for (int fn = 0; fn < 11; ++fn) {
            int col = n0 + fn * 16 + ml;
            if (col < NKV) {
                float bb = bias[col];
#pragma unroll
                for (int r4 = 0; r4 < 4; ++r4) {
                    int row = m0 + wave * 32 + mg * 16 + kg * 4 + r4;
                    kvout[(size_t)row * NKV + col] = __float2bfloat16(acc[mg][fn][r4] + bb);
                }
            }
        }
}

// ---------------- Q projection ------------------------------------------
__global__ __launch_bounds__(192) void proj_q_kernel(
    const float* __restrict__ sf, const int* __restrict__ idx,
    const float* __restrict__ time_b,
    const float* __restrict__ wq, const float* __restrict__ bq,
    float* __restrict__ qout) {
    __shared__ __align__(16) float qin_t[QIN][PAD];
    int base = blockIdx.x * RPB;
    for (int r = 0; r < RPB; r++) {
        int row = base + r;
        const float* src = sf + (size_t)idx[row] * DD;
        for (int i = threadIdx.x; i < QIN; i += blockDim.x) {
            qin_t[i][r] = (i < DD) ? src[i] : cosf(time_b[i - DD]);
        }
    }
    __syncthreads();
    int j = threadIdx.x;
    if (j < DD) {
        float acc[RPB];
#pragma unroll
        for (int r = 0; r < RPB; r++) acc[r] = 0.f;
        for (int i = 0; i < QIN; i++) {
            float w = wq[i * DD + j];
#pragma unroll
            for (int rr = 0; rr < RPB / 4; rr++) {
                float4 a = ((const float4*)&qin_t[i][0])[rr];
                acc[4 * rr + 0] += a.x * w;
                acc[4 * rr + 1] += a.y * w;
                acc[4 * rr + 2] += a.z * w;
                acc[4 * rr + 3] += a.w * w;
            }
        }
        float b = bq[j];
#pragma unroll
        for (int r = 0; r < RPB; r++) qout[(size_t)(base + r) * DD + j] = acc[r] + b;
    }
}

// ---------------- attention over K=20 neighbors (kv packed [row][344]) --
__global__ __launch_bounds__(64) void attn_kernel(
    const float* __restrict__ q, const bf16* __restrict__ kv,
    const void* __restrict__ mask, const int* __restrict__ mode_p,
    float* __restrict__ o) {
    int node = blockIdx.x;
    int tid = threadIdx.x;
    __shared__ float qs[DD];
    __shared__ float sc[HH][KK];
    __shared__ float aw[HH][KK];
    int mode = *mode_p;
    for (int i = tid; i < DD; i += 64) qs[i] = q[(size_t)node * DD + i];
    __syncthreads();
    if (tid < HH * KK) {
        int h = tid / KK, kx = tid % KK;
        bool mk = get_mask(mask, mode, node * KK + kx);
        float s = 0.f;
        const bf16* kr = kv + ((size_t)node * KK + kx) * NKV + h * DHH;
        for (int d = 0; d < DHH; d++) s += qs[h * DHH + d] * __bfloat162float(kr[d]);
        sc[h][kx] = mk ? s * 0.10783277320f : -3.0e38f;
    }
    __syncthreads();
    if (tid < HH) {
        int h = tid;
        float m = -3.0e38f;
        for (int k2 = 0; k2 < KK; k2++) m = fmaxf(m, sc[h][k2]);
        float den = 0.f;
        for (int k2 = 0; k2 < KK; k2++) {
            float e = (sc[h][k2] <= -1e37f) ? 0.f : expf(sc[h][k2] - m);
            sc[h][k2] = e;
            den += e;
        }
        float inv = (den > 0.f) ? 1.f / den : 0.f;
        for (int k2 = 0; k2 < KK; k2++) aw[h][k2] = sc[h][k2] * inv;
    }
    __syncthreads();
    for (int jj = tid; jj < DD; jj += 64) {
        int h = jj / DHH;
        float s = 0.f;
        for (int k2 = 0; k2 < KK; k2++)
            s += aw[h][k2] * __bfloat162float(kv[((size_t)node * KK + k2) * NKV + DD + jj]);
        o[(size_t)node * DD + jj] = s;
    }
}

// ---------------- FFN ---------------------------------------------------
__global__ __launch_bounds__(192) void ffn_kernel(
    const float* __restrict__ o, const float* __restrict__ sf,
    const int* __restrict__ idx,
    const float* __restrict__ f1w, const float* __restrict__ f1b,
    const float* __restrict__ f2w, const float* __restrict__ f2b,
    const int* __restrict__ g2l, float* __restrict__ z) {
    __shared__ __align__(16) float in_t[F1IN][PAD];
    __shared__ __align__(16) float h_t[DD][PAD];
    __shared__ int gid_s[RPB];
    int base = blockIdx.x * RPB;
    if (threadIdx.x < RPB) gid_s[threadIdx.x] = idx[base + threadIdx.x];
    __syncthreads();
    for (int r = 0; r < RPB; r++) {
        int row = base + r;
        const float* src = sf + (size_t)gid_s[r] * DD;
        for (int i = threadIdx.x; i < F1IN; i += blockDim.x)
            in_t[i][r] = (i < DD) ? o[(size_t)row * DD + i] : src[i - DD];
    }
    __syncthreads();
    int j = threadIdx.x;
    if (j < DD) {
        float acc[RPB];
#pragma unroll
        for (int r = 0; r < RPB; r++) acc[r] = 0.f;
        for (int i = 0; i < F1IN; i++) {
            float w = f1w[i * DD + j];
#pragma unroll
            for (int rr = 0; rr < RPB / 4; rr++) {
                float4 a = ((const float4*)&in_t[i][0])[rr];
                acc[4 * rr + 0] += a.x * w;
                acc[4 * rr + 1] += a.y * w;
                acc[4 * rr + 2] += a.z * w;
                acc[4 * rr + 3] += a.w * w;
            }
        }
        float b = f1b[j];
#pragma unroll
        for (int r = 0; r < RPB; r++) h_t[j][r] = fmaxf(acc[r] + b, 0.f);
    }
    __syncthreads();
    if (j < DD) {
        float acc[RPB];
#pragma unroll
        for (int r = 0; r < RPB; r++) acc[r] = 0.f;
        for (int i = 0; i < DD; i++) {
            float w = f2w[i * DD + j];
#pragma unroll
            for (int rr = 0; rr < RPB / 4; rr++) {
                float4 a = ((const float4*)&h_t[i][0])[rr];
                acc[4 * rr + 0] += a.x * w;
                acc[4 * rr + 1] += a.y * w;
                acc[4 * rr + 2] += a.z * w;
                acc[4 * rr + 3] += a.w * w;
            }
        }
        float b = f2b[j];
#pragma unroll
        for (int r = 0; r < RPB; r++) {
            int zr = g2l[gid_s[r]];
            z[(size_t)zr * DD + j] = acc[r] + b;
        }
    }
}

// ---------------- launch ------------------------------------------------
extern "C" void kernel_launch(void* const* d_in, const int* in_sizes, int n_in,
                              void* d_out, int out_size, void* d_ws, size_t ws_size,
                              hipStream_t stream) {
    const float* sf     = (const float*)d_in[0];
    const float* time_w = (const float*)d_in[1];
    const float* time_b = (const float*)d_in[2];
    const float* wq  = (const float*)d_in[3];
    const float* bq  = (const float*)d_in[4];
    const float* wk  = (const float*)d_in[5];
    const float* bk  = (const float*)d_in[6];
    const float* wv  = (const float*)d_in[7];
    const float* bv  = (const float*)d_in[8];
    const float* f1w = (const float*)d_in[9];
    const float* f1b = (const float*)d_in[10];
    const float* f2w = (const float*)d_in[11];
    const float* f2b = (const float*)d_in[12];
    const float* times0 = (const float*)d_in[13];
    const float* nbrt0  = (const float*)d_in[14];
    const float* times1 = (const float*)d_in[15];
    const float* nbrt1  = (const float*)d_in[16];
    const float* edge0  = (const float*)d_in[17];
    const float* edge1  = (const float*)d_in[18];
    const int* nids0 = (const int*)d_in[19];
    const int* nbr0  = (const int*)d_in[20];
    const int* nbr1  = (const int*)d_in[21];
    const int* g2l   = (const int*)d_in[22];
    const void* mask0 = d_in[23];
    const void* mask1 = d_in[24];
    float* z = (float*)d_out;

    char* wsp = (char*)d_ws;
    size_t off = 0;
    auto alloc = [&](size_t bytes) -> void* {
        void* p = wsp + off;
        off += (bytes + 255) & ~(size_t)255;
        return p;
    };
    int*   mode   = (int*)alloc(4);
    bf16*  wkvT   = (bf16*)alloc((size_t)2 * NPADR * KP * sizeof(bf16));
    float* biaskv = (float*)alloc(2 * 352 * sizeof(float));
    float* q1 = (float*)alloc((size_t)N1C * DD * sizeof(float));
    float* o1 = (float*)alloc((size_t)N1C * DD * sizeof(float));
    float* q0 = (float*)alloc((size_t)N0C * DD * sizeof(float));
    float* o0 = (float*)alloc((size_t)N0C * DD * sizeof(float));
    bf16*  kv1 = (bf16*)alloc((size_t)M1 * NKV * sizeof(bf16));
    bf16*  kv0 = (bf16*)alloc((size_t)M0 * NKV * sizeof(bf16));
    // A-chunk takes the remainder of the workspace
    size_t avail = (ws_size > off) ? (ws_size - off) : 0;
    size_t rows_fit = avail / ((size_t)KP * sizeof(bf16));
    long chunkRows = (long)((rows_fit / BM) * BM);
    if (chunkRows > M1) chunkRows = M1;
    if (chunkRows < BM) chunkRows = BM;   // minimal fallback
    bf16* Achunk = (bf16*)(wsp + off);

    probe_mask_kernel<<<1, 256, 0, stream>>>((const unsigned*)mask1, (N1C * KK) / 4, mode);
    {
        size_t tot = (size_t)2 * NPADR * KP;
        prep_wkvT_kernel<<<(int)((tot + 255) / 256), 256, 0, stream>>>(wk, wv, bk, bv, wkvT, biaskv);
    }

    // ---- layer 1 ----
    proj_q_kernel<<<N1C / RPB, 192, 0, stream>>>(
        sf, nbr0, time_b, wq + (size_t)QIN * DD, bq + DD, q1);
    for (long r0 = 0; r0 < M1; r0 += chunkRows) {
        long rows = M1 - r0 < chunkRows ? M1 - r0 : chunkRows;
        stage_kvin_kernel<<<(int)(rows / 4), 256, 0, stream>>>(
            sf, nbr1, edge1, times1, nbrt1, mask1, mode, time_w, time_b,
            nullptr, g2l, 0, (int)r0, Achunk);
        gemm_kv_kernel<<<(int)((rows / BM) * 2), 256, 0, stream>>>(
            Achunk, wkvT + (size_t)NPADR * KP, biaskv + 352,
            kv1 + (size_t)r0 * NKV, (int)(rows / BM));
    }
    attn_kernel<<<N1C, 64, 0, stream>>>(q1, kv1, mask1, mode, o1);
    ffn_kernel<<<N1C / RPB, 192, 0, stream>>>(
        o1, sf, nbr0, f1w + (size_t)F1IN * DD, f1b + DD,
        f2w + (size_t)DD * DD, f2b + DD, g2l, z);

    // ---- layer 0 ----
    proj_q_kernel<<<N0C / RPB, 192, 0, stream>>>(
        sf, nids0, time_b, wq, bq, q0);
    for (long r0 = 0; r0 < M0; r0 += chunkRows) {
        long rows = M0 - r0 < chunkRows ? M0 - r0 : chunkRows;
        stage_kvin_kernel<<<(int)(rows / 4), 256, 0, stream>>>(
            sf, nbr0, edge0, times0, nbrt0, mask0, mode, time_w, time_b,
            z, g2l, 1, (int)r0, Achunk);
        gemm_kv_kernel<<<(int)((rows / BM) * 2), 256, 0, stream>>>(
            Achunk, wkvT, biaskv,
            kv0 + (size_t)r0 * NKV, (int)(rows / BM));
    }
    attn_kernel<<<N0C, 64, 0, stream>>>(q0, kv0, mask0, mode, o0);
    ffn_kernel<<<N0C / RPB, 192, 0, stream>>>(
        o0, sf, nids0, f1w, f1b, f2w, f2b, g2l, z);
}

// Round 3
// 594.118 us; speedup vs baseline: 2.6015x; 1.2104x over previous
//
#include <hip/hip_runtime.h>
#include <hip/hip_bf16.h>

typedef __hip_bfloat16 bf16;
typedef __attribute__((ext_vector_type(8))) short short8;
typedef __attribute__((ext_vector_type(4))) float f32x4;

#define DD    172      // D
#define EE    172      // E
#define TT    100      // T
#define HH    2
#define KK    20
#define DHH   86
#define QIN   272      // D+T
#define N0C   512
#define N1C   10240
#define M1    204800   // N1*K rows
#define M0    10240    // N0*K rows

// GEMM geometry
#define BM   128
#define BN   176
#define BK   64
#define KP   448       // padded K for kv gemm (444 -> 448)
#define NKV  344       // real N (k|v)
#define NPADR 384      // wkvT rows per layer
#define QS   320       // qin padded K
#define F1S  384       // f1in padded K
#define HS   192       // h padded K

#define GLOAD(src, dst) __builtin_amdgcn_global_load_lds( \
    (const __attribute__((address_space(1))) unsigned int*)(src), \
    (__attribute__((address_space(3))) unsigned int*)(dst), 16, 0, 0)

__device__ __forceinline__ float bfu2f(unsigned short u) {
    return __uint_as_float(((unsigned)u) << 16);
}

// ---------------- mask dtype probe -------------------------------------
__global__ void probe_mask_kernel(const unsigned* __restrict__ m, int n_ints,
                                  int* __restrict__ mode_out) {
    __shared__ int c_other, c_float;
    if (threadIdx.x == 0) { c_other = 0; c_float = 0; }
    __syncthreads();
    int lo = 0, lf = 0;
    for (int i = threadIdx.x; i < n_ints; i += blockDim.x) {
        unsigned v = m[i];
        if (v == 0x3F800000u) lf++;
        else if (v > 1u) lo++;
    }
    if (lo) atomicAdd(&c_other, lo);
    if (lf) atomicAdd(&c_float, lf);
    __syncthreads();
    if (threadIdx.x == 0) {
        int mode = 0;
        if (c_float > 0) mode = 2;
        else if (c_other > 0) mode = 1;
        *mode_out = mode;
    }
}

__device__ __forceinline__ bool get_mask(const void* m, int mode, int idx) {
    if (mode == 1) return ((const unsigned char*)m)[idx] != 0;
    if (mode == 2) return ((const float*)m)[idx] != 0.0f;
    return ((const int*)m)[idx] != 0;
}

// ---------------- weight prep: wkvT[l][n][k] bf16 + fused bias ----------
__global__ void prep_wkvT_kernel(const float* __restrict__ wk, const float* __restrict__ wv,
                                 const float* __restrict__ bk, const float* __restrict__ bv,
                                 bf16* __restrict__ wkvT, float* __restrict__ biaskv) {
    size_t i = (size_t)blockIdx.x * blockDim.x + threadIdx.x;
    size_t tot = (size_t)2 * NPADR * KP;
    if (i >= tot) return;
    int l = (int)(i / ((size_t)NPADR * KP));
    int rem = (int)(i % ((size_t)NPADR * KP));
    int k = rem / NPADR;
    int n = rem % NPADR;
    float v = 0.f;
    if (k < 444) {
        if (n < DD)          v = wk[((size_t)l * 444 + k) * DD + n];
        else if (n < 2 * DD) v = wv[((size_t)l * 444 + k) * DD + (n - DD)];
    }
    wkvT[((size_t)l * NPADR + n) * KP + k] = __float2bfloat16(v);
    if (i < 2 * 352) {
        int nn = (int)(i % 352), ll = (int)(i / 352);
        biaskv[i] = nn < DD ? bk[ll * DD + nn] : (nn < 2 * DD ? bv[ll * DD + nn - DD] : 0.f);
    }
}

// ---------------- generic weight transpose: W[K][172] -> dstT[192][KPdst]
__global__ void prep_wT_kernel(const float* __restrict__ W, const float* __restrict__ b,
                               int K, int KPdst,
                               bf16* __restrict__ dstT, float* __restrict__ biasdst) {
    int i = blockIdx.x * blockDim.x + threadIdx.x;
    int tot = 192 * KPdst;
    if (i < tot) {
        int n = i / KPdst, k = i % KPdst;
        float v = (n < DD && k < K) ? W[(size_t)k * DD + n] : 0.f;
        dstT[(size_t)n * KPdst + k] = __float2bfloat16(v);
    }
    if (i < 176) biasdst[i] = (i < DD) ? b[i] : 0.f;
}

// ---------------- kv_in staging: [nbr_feat | edge | cos(dt*w+b) | 0pad] --
__global__ __launch_bounds__(256) void stage_kvin_kernel(
    const float* __restrict__ sf, const int* __restrict__ nbrs,
    const float* __restrict__ edge, const float* __restrict__ times,
    const float* __restrict__ nbrt,
    const void* __restrict__ mask, const int* __restrict__ mode_p,
    const float* __restrict__ time_w, const float* __restrict__ time_b,
    const float* __restrict__ zbuf, const int* __restrict__ g2l, int use_z,
    int row0, bf16* __restrict__ out) {
    int wave = threadIdx.x >> 6, lane = threadIdx.x & 63;
    int lrow = blockIdx.x * 4 + wave;
    int row = row0 + lrow;
    int mode = *mode_p;
    int g = nbrs[row];
    bool mk = get_mask(mask, mode, row);
    float dt = mk ? (times[row / KK] - nbrt[row]) : 0.f;
    const float* src = (use_z && mk) ? (zbuf + (size_t)g2l[g] * DD)
                                     : (sf + (size_t)g * DD);
    const float* erow = edge + (size_t)row * EE;
    bf16* orow = out + (size_t)lrow * KP;
    for (int i = lane; i < KP; i += 64) {
        float v;
        if (i < DD)            v = src[i];
        else if (i < DD + EE)  v = erow[i - DD];
        else if (i < 444)      { int t = i - DD - EE; v = cosf(dt * time_w[t] + time_b[t]); }
        else                   v = 0.f;
        orow[i] = __float2bfloat16(v);
    }
}

// ---------------- q_in staging: [feat | cos(time_b) | 0pad] -------------
__global__ __launch_bounds__(256) void stage_qin_kernel(
    const float* __restrict__ sf, const int* __restrict__ idx,
    const float* __restrict__ time_b, bf16* __restrict__ out) {
    int wave = threadIdx.x >> 6, lane = threadIdx.x & 63;
    int row = blockIdx.x * 4 + wave;
    const float* src = sf + (size_t)idx[row] * DD;
    bf16* orow = out + (size_t)row * QS;
    for (int i = lane; i < QS; i += 64) {
        float v;
        if (i < DD)        v = src[i];
        else if (i < QIN)  v = cosf(time_b[i - DD]);
        else               v = 0.f;
        orow[i] = __float2bfloat16(v);
    }
}

// ---------------- MFMA GEMM (kv): kv[m][0:344] = A @ wkvT^T + bias ------
__global__ __launch_bounds__(256) void gemm_kv_kernel(
    const bf16* __restrict__ A, const bf16* __restrict__ BT,
    const float* __restrict__ bias, bf16* __restrict__ kvout, int Mtiles) {
    int mt = blockIdx.x % Mtiles;
    int nt = blockIdx.x / Mtiles;
    int m0 = mt * BM;
    int n0 = nt * BN;
    __shared__ bf16 As[BM][BK];
    __shared__ bf16 Bs[192][BK];
    int tid = threadIdx.x;
    int lane = tid & 63;
    int wave = tid >> 6;
    int ml = lane & 15;
    int kg = lane >> 4;

    f32x4 acc[2][11];
#pragma unroll
    for (int mg = 0; mg < 2; ++mg)
#pragma unroll
        for (int fn = 0; fn < 11; ++fn)
            acc[mg][fn] = (f32x4){0.f, 0.f, 0.f, 0.f};

    for (int kk = 0; kk < KP; kk += BK) {
        int c0 = tid;
#pragma unroll
        for (int it = 0; it < 4; ++it) {
            int c = it * 256 + c0;
            int row = c >> 3, slot = c & 7;
            int sslot = slot ^ (row & 7);
            const bf16* src = A + (size_t)(m0 + row) * KP + kk + sslot * 8;
            char* dst = ((char*)As) + (size_t)(it * 256 + wave * 64) * 16;
            GLOAD(src, dst);
        }
#pragma unroll
        for (int it = 0; it < 6; ++it) {
            int c = it * 256 + c0;
            int row = c >> 3, slot = c & 7;
            int sslot = slot ^ (row & 7);
            const bf16* src = BT + (size_t)(n0 + row) * KP + kk + sslot * 8;
            char* dst = ((char*)Bs) + (size_t)(it * 256 + wave * 64) * 16;
            GLOAD(src, dst);
        }
        __syncthreads();
#pragma unroll
        for (int half = 0; half < 2; ++half) {
            int kc = kg + half * 4;
            short8 a[2], b[11];
#pragma unroll
            for (int mg = 0; mg < 2; ++mg) {
                int r = wave * 32 + mg * 16 + ml;
                a[mg] = *(const short8*)(((const char*)As) + (size_t)r * 128 + ((size_t)(kc ^ (r & 7)) << 4));
            }
#pragma unroll
            for (int fn = 0; fn < 11; ++fn) {
                int r = fn * 16 + ml;
                b[fn] = *(const short8*)(((const char*)Bs) + (size_t)r * 128 + ((size_t)(kc ^ (r & 7)) << 4));
            }
#pragma unroll
            for (int mg = 0; mg < 2; ++mg)
#pragma unroll
                for (int fn = 0; fn < 11; ++fn)
                    acc[mg][fn] = __builtin_amdgcn_mfma_f32_16x16x32_bf16(a[mg], b[fn], acc[mg][fn], 0, 0, 0);
        }
        __syncthreads();
    }
#pragma unroll
    for (int mg = 0; mg < 2; ++mg)
#pragma unroll
        for (int fn = 0; fn < 11; ++fn) {
            int col = n0 + fn * 16 + ml;
            if (col < NKV) {
                float bb = bias[col];
#pragma unroll
                for (int r4 = 0; r4 < 4; ++r4) {
                    int row = m0 + wave * 32 + mg * 16 + kg * 4 + r4;
                    kvout[(size_t)row * NKV + col] = __float2bfloat16(acc[mg][fn][r4] + bb);
                }
            }
        }
}

// ---------------- generic 176-col MFMA GEMM -----------------------------
// OMODE: 0 = bf16 dense (stride ostride, zero pad cols 176..ostride),
//        1 = fp32 dense (cols < 172), 2 = fp32 scatter rows via g2l[idx[row]]
template<int KP_, bool RELU, int OMODE>
__global__ __launch_bounds__(256) void gemm176_kernel(
    const bf16* __restrict__ A, const bf16* __restrict__ BT,
    const float* __restrict__ bias, void* __restrict__ outp, int ostride,
    const int* __restrict__ idx, const int* __restrict__ g2l) {
    int m0 = blockIdx.x * BM;
    __shared__ bf16 As[BM][BK];
    __shared__ bf16 Bs[192][BK];
    int tid = threadIdx.x;
    int lane = tid & 63;
    int wave = tid >> 6;
    int ml = lane & 15;
    int kg = lane >> 4;

    f32x4 acc[2][11];
#pragma unroll
    for (int mg = 0; mg < 2; ++mg)
#pragma unroll
        for (int fn = 0; fn < 11; ++fn)
            acc[mg][fn] = (f32x4){0.f, 0.f, 0.f, 0.f};

    for (int kk = 0; kk < KP_; kk += BK) {
        int c0 = tid;
#pragma unroll
        for (int it = 0; it < 4; ++it) {
            int c = it * 256 + c0;
            int row = c >> 3, slot = c & 7;
            int sslot = slot ^ (row & 7);
            const bf16* src = A + (size_t)(m0 + row) * KP_ + kk + sslot * 8;
            char* dst = ((char*)As) + (size_t)(it * 256 + wave * 64) * 16;
            GLOAD(src, dst);
        }
#pragma unroll
        for (int it = 0; it < 6; ++it) {
            int c = it * 256 + c0;
            int row = c >> 3, slot = c & 7;
            int sslot = slot ^ (row & 7);
            const bf16* src = BT + (size_t)row * KP_ + kk + sslot * 8;
            char* dst = ((char*)Bs) + (size_t)(it * 256 + wave * 64) * 16;
            GLOAD(src, dst);
        }
        __syncthreads();
#pragma unroll
        for (int half = 0; half < 2; ++half) {
            int kc = kg + half * 4;
            short8 a[2], b[11];
#pragma unroll
            for (int mg = 0; mg < 2; ++mg) {
                int r = wave * 32 + mg * 16 + ml;
                a[mg] = *(const short8*)(((const char*)As) + (size_t)r * 128 + ((size_t)(kc ^ (r & 7)) << 4));
            }
#pragma unroll
            for (int fn = 0; fn < 11; ++fn) {
                int r = fn * 16 + ml;
                b[fn] = *(const short8*)(((const char*)Bs) + (size_t)r * 128 + ((size_t)(kc ^ (r & 7)) << 4));
            }
#pragma unroll
            for (int mg = 0; mg < 2; ++mg)
#pragma unroll
                for (int fn = 0; fn < 11; ++fn)
                    acc[mg][fn] = __builtin_amdgcn_mfma_f32_16x16x32_bf16(a[mg], b[fn], acc[mg][fn], 0, 0, 0);
        }
        __syncthreads();
    }
#pragma unroll
    for (int mg = 0; mg < 2; ++mg)
#pragma unroll
        for (int fn = 0; fn < 11; ++fn) {
            int col = fn * 16 + ml;
            float bb = bias[col];
#pragma unroll
            for (int r4 = 0; r4 < 4; ++r4) {
                int row = m0 + wave * 32 + mg * 16 + kg * 4 + r4;
                float v = acc[mg][fn][r4] + bb;
                if (RELU) v = fmaxf(v, 0.f);
                if (OMODE == 0) {
                    ((bf16*)outp)[(size_t)row * ostride + col] = __float2bfloat16(v);
                } else if (OMODE == 1) {
                    if (col < DD) ((float*)outp)[(size_t)row * ostride + col] = v;
                } else {
                    if (col < DD) {
                        int zr = g2l[idx[row]];
                        ((float*)outp)[(size_t)zr * DD + col] = v;
                    }
                }
            }
        }
    if (OMODE == 0 && ostride > 176) {
        // zero pad cols [176, ostride) — 16 cols, 2 x short8 per row
        int row = tid >> 1, half = tid & 1;
        short8 zz = (short8){0, 0, 0, 0, 0, 0, 0, 0};
        *(short8*)&((bf16*)outp)[(size_t)(m0 + row) * ostride + 176 + half * 8] = zz;
    }
}

// ---------------- attention over K=20 neighbors -------------------------
// Stages contiguous 20x344 bf16 KV block to LDS (short8), computes softmax-
// attention, writes o (bf16) + gathered nf + zero pad into f1in[row][F1S].
#define ASTR 360
__global__ __launch_bounds__(64) void attn_kernel(
    const float* __restrict__ q, const bf16* __restrict__ kv,
    const void* __restrict__ mask, const int* __restrict__ mode_p,
    const float* __restrict__ sf, const int* __restrict__ idx,
    bf16* __restrict__ f1out) {
    int node = blockIdx.x;
    int lane = threadIdx.x;
    __shared__ unsigned short kvls[KK][ASTR];
    __shared__ float qs[DD];
    __shared__ float sc[HH][KK];
    __shared__ float aw[HH][KK];
    int mode = *mode_p;
    const unsigned short* kvg = (const unsigned short*)(kv + (size_t)node * KK * NKV);
    for (int c = lane; c < 860; c += 64) {          // 20*344/8 = 860 chunks
        int r = c / 43, cc = c % 43;
        *(short8*)&kvls[r][cc * 8] = *(const short8*)(kvg + (size_t)c * 8);
    }
    for (int i = lane; i < DD; i += 64) qs[i] = q[(size_t)node * DD + i];
    __syncthreads();
    if (lane < HH * KK) {
        int h = lane / KK, kx = lane % KK;
        bool mk = get_mask(mask, mode, node * KK + kx);
        float s = 0.f;
        const unsigned short* kr = &kvls[kx][h * DHH];
        for (int d = 0; d < DHH; d++) s += qs[h * DHH + d] * bfu2f(kr[d]);
        sc[h][kx] = mk ? s * 0.10783277320f : -3.0e38f;
    }
    __syncthreads();
    if (lane < HH) {
        int h = lane;
        float m = -3.0e38f;
        for (int k2 = 0; k2 < KK; k2++) m = fmaxf(m, sc[h][k2]);
        float den = 0.f;
        for (int k2 = 0; k2 < KK; k2++) {
            float e = (sc[h][k2] <= -1e37f) ? 0.f : expf(sc[h][k2] - m);
            sc[h][k2] = e;
            den += e;
        }
        float inv = (den > 0.f) ? 1.f / den : 0.f;
        for (int k2 = 0; k2 < KK; k2++) aw[h][k2] = sc[h][k2] * inv;
    }
    __syncthreads();
    bf16* orow = f1out + (size_t)node * F1S;
    for (int jj = lane; jj < DD; jj += 64) {
        int h = jj / DHH;
        float s = 0.f;
        for (int k2 = 0; k2 < KK; k2++)
            s += aw[h][k2] * bfu2f(kvls[k2][DD + jj]);
        orow[jj] = __float2bfloat16(s);
    }
    const float* src = sf + (size_t)idx[node] * DD;
    for (int c = lane; c < F1S - DD; c += 64) {     // cols 172..383: nf then 0
        float v = (c < DD) ? src[c] : 0.f;
        orow[DD + c] = __float2bfloat16(v);
    }
}

// ---------------- launch ------------------------------------------------
extern "C" void kernel_launch(void* const* d_in, const int* in_sizes, int n_in,
                              void* d_out, int out_size, void* d_ws, size_t ws_size,
                              hipStream_t stream) {
    const float* sf     = (const float*)d_in[0];
    const float* time_w = (const float*)d_in[1];
    const float* time_b = (const float*)d_in[2];
    const float* wq  = (const float*)d_in[3];
    const float* bq  = (const float*)d_in[4];
    const float* wk  = (const float*)d_in[5];
    const float* bk  = (const float*)d_in[6];
    const float* wv  = (const float*)d_in[7];
    const float* bv  = (const float*)d_in[8];
    const float* f1w = (const float*)d_in[9];
    const float* f1b = (const float*)d_in[10];
    const float* f2w = (const float*)d_in[11];
    const float* f2b = (const float*)d_in[12];
    const float* times0 = (const float*)d_in[13];
    const float* nbrt0  = (const float*)d_in[14];
    const float* times1 = (const float*)d_in[15];
    const float* nbrt1  = (const float*)d_in[16];
    const float* edge0  = (const float*)d_in[17];
    const float* edge1  = (const float*)d_in[18];
    const int* nids0 = (const int*)d_in[19];
    const int* nbr0  = (const int*)d_in[20];
    const int* nbr1  = (const int*)d_in[21];
    const int* g2l   = (const int*)d_in[22];
    const void* mask0 = d_in[23];
    const void* mask1 = d_in[24];
    float* z = (float*)d_out;

    char* wsp = (char*)d_ws;
    size_t off = 0;
    auto alloc = [&](size_t bytes) -> void* {
        void* p = wsp + off;
        off += (bytes + 255) & ~(size_t)255;
        return p;
    };
    int*   mode   = (int*)alloc(4);
    bf16*  wkvT   = (bf16*)alloc((size_t)2 * NPADR * KP * sizeof(bf16));
    float* biaskv = (float*)alloc(2 * 352 * sizeof(float));
    bf16*  wqT    = (bf16*)alloc((size_t)2 * 192 * QS * sizeof(bf16));
    float* biasq  = (float*)alloc(2 * 176 * sizeof(float));
    bf16*  f1T    = (bf16*)alloc((size_t)2 * 192 * F1S * sizeof(bf16));
    float* biasf1 = (float*)alloc(2 * 176 * sizeof(float));
    bf16*  f2T    = (bf16*)alloc((size_t)2 * 192 * HS * sizeof(bf16));
    float* biasf2 = (float*)alloc(2 * 176 * sizeof(float));
    bf16*  qin1 = (bf16*)alloc((size_t)N1C * QS * sizeof(bf16));
    bf16*  qin0 = (bf16*)alloc((size_t)N0C * QS * sizeof(bf16));
    float* q1 = (float*)alloc((size_t)N1C * DD * sizeof(float));
    float* q0 = (float*)alloc((size_t)N0C * DD * sizeof(float));
    bf16*  f1in1 = (bf16*)alloc((size_t)N1C * F1S * sizeof(bf16));
    bf16*  f1in0 = (bf16*)alloc((size_t)N0C * F1S * sizeof(bf16));
    bf16*  h1 = (bf16*)alloc((size_t)N1C * HS * sizeof(bf16));
    bf16*  h0 = (bf16*)alloc((size_t)N0C * HS * sizeof(bf16));
    bf16*  kv1 = (bf16*)alloc((size_t)M1 * NKV * sizeof(bf16));
    bf16*  kv0 = (bf16*)alloc((size_t)M0 * NKV * sizeof(bf16));
    size_t avail = (ws_size > off) ? (ws_size - off) : 0;
    size_t rows_fit = avail / ((size_t)KP * sizeof(bf16));
    long chunkRows = (long)((rows_fit / BM) * BM);
    if (chunkRows > M1) chunkRows = M1;
    if (chunkRows < BM) chunkRows = BM;
    bf16* Achunk = (bf16*)(wsp + off);

    probe_mask_kernel<<<1, 256, 0, stream>>>((const unsigned*)mask1, (N1C * KK) / 4, mode);
    {
        size_t tot = (size_t)2 * NPADR * KP;
        prep_wkvT_kernel<<<(int)((tot + 255) / 256), 256, 0, stream>>>(wk, wv, bk, bv, wkvT, biaskv);
    }
    for (int l = 0; l < 2; l++) {
        prep_wT_kernel<<<(192 * QS + 255) / 256, 256, 0, stream>>>(
            wq + (size_t)l * QIN * DD, bq + (size_t)l * DD, QIN, QS,
            wqT + (size_t)l * 192 * QS, biasq + l * 176);
        prep_wT_kernel<<<(192 * F1S + 255) / 256, 256, 0, stream>>>(
            f1w + (size_t)l * 344 * DD, f1b + (size_t)l * DD, 344, F1S,
            f1T + (size_t)l * 192 * F1S, biasf1 + l * 176);
        prep_wT_kernel<<<(192 * HS + 255) / 256, 256, 0, stream>>>(
            f2w + (size_t)l * DD * DD, f2b + (size_t)l * DD, DD, HS,
            f2T + (size_t)l * 192 * HS, biasf2 + l * 176);
    }

    // ---- layer 1 ----
    stage_qin_kernel<<<N1C / 4, 256, 0, stream>>>(sf, nbr0, time_b, qin1);
    gemm176_kernel<QS, false, 1><<<N1C / BM, 256, 0, stream>>>(
        qin1, wqT + (size_t)192 * QS, biasq + 176, q1, DD, nullptr, nullptr);
    for (long r0 = 0; r0 < M1; r0 += chunkRows) {
        long rows = M1 - r0 < chunkRows ? M1 - r0 : chunkRows;
        stage_kvin_kernel<<<(int)(rows / 4), 256, 0, stream>>>(
            sf, nbr1, edge1, times1, nbrt1, mask1, mode, time_w, time_b,
            nullptr, g2l, 0, (int)r0, Achunk);
        gemm_kv_kernel<<<(int)((rows / BM) * 2), 256, 0, stream>>>(
            Achunk, wkvT + (size_t)NPADR * KP, biaskv + 352,
            kv1 + (size_t)r0 * NKV, (int)(rows / BM));
    }
    attn_kernel<<<N1C, 64, 0, stream>>>(q1, kv1, mask1, mode, sf, nbr0, f1in1);
    gemm176_kernel<F1S, true, 0><<<N1C / BM, 256, 0, stream>>>(
        f1in1, f1T + (size_t)192 * F1S, biasf1 + 176, h1, HS, nullptr, nullptr);
    gemm176_kernel<HS, false, 2><<<N1C / BM, 256, 0, stream>>>(
        h1, f2T + (size_t)192 * HS, biasf2 + 176, z, DD, nbr0, g2l);

    // ---- layer 0 ----
    stage_qin_kernel<<<N0C / 4, 256, 0, stream>>>(sf, nids0, time_b, qin0);
    gemm176_kernel<QS, false, 1><<<N0C / BM, 256, 0, stream>>>(
        qin0, wqT, biasq, q0, DD, nullptr, nullptr);
    for (long r0 = 0; r0 < M0; r0 += chunkRows) {
        long rows = M0 - r0 < chunkRows ? M0 - r0 : chunkRows;
        stage_kvin_kernel<<<(int)(rows / 4), 256, 0, stream>>>(
            sf, nbr0, edge0, times0, nbrt0, mask0, mode, time_w, time_b,
            z, g2l, 1, (int)r0, Achunk);
        gemm_kv_kernel<<<(int)((rows / BM) * 2), 256, 0, stream>>>(
            Achunk, wkvT, biaskv,
            kv0 + (size_t)r0 * NKV, (int)(rows / BM));
    }
    attn_kernel<<<N0C, 64, 0, stream>>>(q0, kv0, mask0, mode, sf, nids0, f1in0);
    gemm176_kernel<F1S, true, 0><<<N0C / BM, 256, 0, stream>>>(
        f1in0, f1T, biasf1, h0, HS, nullptr, nullptr);
    gemm176_kernel<HS, false, 2><<<N0C / BM, 256, 0, stream>>>(
        h0, f2T, biasf2, z, DD, nids0, g2l);
}